// Round 3
// baseline (499.760 us; speedup 1.0000x reference)
//
#include <hip/hip_runtime.h>
#include <math.h>

#define BGR 64          // graphs
#define N0 512          // nodes/graph at level 1
#define NDEG 16
#define E_TOT (BGR*N0*NDEG)   // 524288 edge slots, fixed across levels
#define EPG (N0*NDEG)         // 8192 edge slots per graph at every level
#define HID 128

static inline int cdiv(int a, int b){ return (a+b-1)/b; }

// ---- XCD-aware swizzles: graph g is pinned to XCD g/8 (blockIdx%8 -> XCD heuristic)

// copy edges; src = -1 marks dead edges in later levels. Also zero cnt and z.
__global__ void k_edge_init(const int* __restrict__ s0, const int* __restrict__ d0,
                            int* __restrict__ s, int* __restrict__ d,
                            int* __restrict__ cnt, float* __restrict__ z){
  int i = blockIdx.x*blockDim.x + threadIdx.x;
  if (i < E_TOT){ s[i] = s0[i]; d[i] = d0[i]; }
  if (i < 32768) cnt[i] = 0;
  if (i < BGR*256) z[i] = 0.f;
}

// h = x @ W, 8 nodes per 128-thread block (reuse W across nodes), XCD-pinned
__global__ void k_gemm8(const float* __restrict__ x, const float* __restrict__ W,
                        float* __restrict__ out, int fin, int nper){
  __shared__ float xr[8][HID];
  int b = blockIdx.x;
  int xcd = b & 7, idx = b >> 3, bpg = nper >> 3;     // 8-node blocks per graph
  int graph = xcd*8 + idx / bpg;
  int base = graph*nper + (idx % bpg)*8;
  int f = threadIdx.x;
  #pragma unroll
  for (int nd = 0; nd < 8; nd++) if (f < fin) xr[nd][f] = x[(base+nd)*fin + f];
  __syncthreads();
  float acc[8] = {0,0,0,0,0,0,0,0};
  for (int i = 0; i < fin; i++){
    float wv = W[i*HID + f];
    #pragma unroll
    for (int nd = 0; nd < 8; nd++) acc[nd] += xr[nd][i]*wv;
  }
  #pragma unroll
  for (int nd = 0; nd < 8; nd++) out[(base+nd)*HID + f] = acc[nd];
}

// degree count over edge slots (grid = E_TOT/256, XCD-pinned: 32 blocks/graph)
__global__ void k_deg_cnt(const int* __restrict__ src, const int* __restrict__ dst,
                          int* __restrict__ cnt){
  int b = blockIdx.x;
  int xcd = b & 7, idx = b >> 3;
  int graph = xcd*8 + (idx >> 5);
  int i = graph*EPG + (idx & 31)*256 + threadIdx.x;
  int s = src[i];
  if (s >= 0) atomicAdd(&cnt[dst[i]], 1);
}

// per-graph exclusive scan of cnt -> rowptr & cursor; fused dinv = rsqrt(cnt+1)
__global__ void k_scan(const int* __restrict__ cnt, int* __restrict__ rowptr,
                       int* __restrict__ cursor, float* __restrict__ dinv, int nper){
  __shared__ int sb[512];
  int g = (blockIdx.x & 7)*8 + (blockIdx.x >> 3);     // graph g on XCD g/8
  int t = threadIdx.x;
  int v = (t < nper) ? cnt[g*nper + t] : 0;
  sb[t] = v; __syncthreads();
  for (int off = 1; off < nper; off <<= 1){
    int add = (t >= off) ? sb[t-off] : 0;
    __syncthreads();
    sb[t] += add;
    __syncthreads();
  }
  if (t < nper){
    int excl = sb[t] - v;
    rowptr[g*nper + t] = g*EPG + excl;
    cursor[g*nper + t] = g*EPG + excl;
    dinv[g*nper + t] = rsqrtf((float)v + 1.0f);       // +1 self-loop
  }
}

// pack each live edge as {src, bitcast(dinv[s]*dinv[d])} into dst's CSR row
__global__ void k_csr_fill(const int* __restrict__ src, const int* __restrict__ dst,
                           const float* __restrict__ dinv, int* __restrict__ cursor,
                           int2* __restrict__ csr){
  int b = blockIdx.x;
  int xcd = b & 7, idx = b >> 3;
  int graph = xcd*8 + (idx >> 5);
  int i = graph*EPG + (idx & 31)*256 + threadIdx.x;
  int s = src[i];
  if (s >= 0){
    int d = dst[i];
    int pos = atomicAdd(&cursor[d], 1);
    csr[pos] = make_int2(s, __float_as_int(dinv[s]*dinv[d]));
  }
}

// gather GCN: 2 nodes x 128 feats per block, XCD-pinned; fused bias+relu and hp=row.Wp
__global__ __launch_bounds__(256) void k_gcn_gather(
    const float* __restrict__ h, const int2* __restrict__ csr,
    const int* __restrict__ rowptr, const int* __restrict__ cnt,
    const float* __restrict__ dinv, const float* __restrict__ bias,
    const float* __restrict__ Wp, float* __restrict__ out, float* __restrict__ hp,
    int nper){
  __shared__ float hpart[4];
  int b = blockIdx.x;
  int xcd = b & 7, idx = b >> 3, bpg = nper >> 1;     // node-pair blocks per graph
  int graph = xcd*8 + idx / bpg;
  int pair = idx % bpg;
  int tid = threadIdx.x;
  int sub = tid >> 7, f = tid & 127;
  int node = graph*nper + pair*2 + sub;
  int start = rowptr[node], c = cnt[node];
  float acc = 0.f;
  if (c > 0){
    int2 e = csr[start];
    for (int j = 1; j < c; j++){
      int2 en = csr[start + j];
      acc += __int_as_float(e.y) * h[e.x*HID + f];
      e = en;
    }
    acc += __int_as_float(e.y) * h[e.x*HID + f];
  }
  float di = dinv[node];
  float v = acc + h[node*HID + f]*di*di + bias[f];
  v = fmaxf(v, 0.f);
  out[node*HID + f] = v;
  // hp[node] = dot(out_row, Wp)
  float contrib = v * Wp[f];
  #pragma unroll
  for (int off = 32; off; off >>= 1) contrib += __shfl_down(contrib, off, 64);
  if ((tid & 63) == 0) hpart[tid >> 6] = contrib;
  __syncthreads();
  if (f == 0) hp[node] = hpart[sub*2] + hpart[sub*2 + 1];
}

// per-graph: edge-parallel score agg (LDS atomics) -> tanh -> bitonic top-k ->
// pooled features, mapping, fused max/mean readout into z. XCD-pinned.
__global__ void k_pool(const float* __restrict__ gout, const float* __restrict__ hp,
                       const int* __restrict__ src, const int* __restrict__ dst,
                       const float* __restrict__ dinv, const float* __restrict__ bp,
                       float* __restrict__ xpool, int* __restrict__ mapping,
                       float* __restrict__ z, int nper){
  __shared__ float sacc[512];
  __shared__ float sv[512];
  __shared__ int   si[512];
  __shared__ float redmx[2][128];
  __shared__ float redsm[2][128];
  int g = (blockIdx.x & 7)*8 + (blockIdx.x >> 3);     // graph g on XCD g/8
  int tid = threadIdx.x;
  int k = nper >> 1, gbase = g*nper, ebase = g*EPG;
  for (int ln = tid; ln < nper; ln += 256) sacc[ln] = 0.f;
  __syncthreads();
  for (int e = tid; e < EPG; e += 256){
    int s = src[ebase + e];
    if (s >= 0){
      int d = dst[ebase + e];
      atomicAdd(&sacc[d - gbase], hp[s]*dinv[s]*dinv[d]);
    }
  }
  __syncthreads();
  for (int ln = tid; ln < nper; ln += 256){
    int node = gbase + ln;
    float di = dinv[node];
    sv[ln] = tanhf(sacc[ln] + hp[node]*di*di + bp[0]);
    si[ln] = ln;
    mapping[node] = -1;
  }
  __syncthreads();
  // bitonic sort desc by value, ties -> lower index first (matches jax top_k)
  for (int kk = 2; kk <= nper; kk <<= 1){
    for (int jj = kk >> 1; jj > 0; jj >>= 1){
      for (int i = tid; i < nper; i += 256){
        int ixj = i ^ jj;
        if (ixj > i){
          float av = sv[i], bv = sv[ixj];
          int   ai = si[i], bi = si[ixj];
          bool worseA = (av < bv) || (av == bv && ai > bi);
          bool dir = ((i & kk) == 0);
          bool sw = dir ? worseA : !worseA;
          if (sw){ sv[i] = bv; si[i] = bi; sv[ixj] = av; si[ixj] = ai; }
        }
      }
      __syncthreads();
    }
  }
  // pooled features + readout partials
  int f = tid & 127, jh = tid >> 7;
  float mx = -INFINITY, sm = 0.f;
  for (int j = jh; j < k; j += 2){
    float v = gout[(gbase + si[j])*HID + f] * sv[j];
    xpool[(g*k + j)*HID + f] = v;
    mx = fmaxf(mx, v); sm += v;
  }
  redmx[jh][f] = mx; redsm[jh][f] = sm;
  __syncthreads();
  if (jh == 0){
    z[g*256 + f]       += fmaxf(redmx[0][f], redmx[1][f]);
    z[g*256 + 128 + f] += (redsm[0][f] + redsm[1][f]) / (float)k;
  }
  for (int j = tid; j < k; j += 256) mapping[gbase + si[j]] = g*k + j;
}

// relabel edges for next level; also zero cnt for next level's degree count
__global__ void k_relabel(int* __restrict__ src, int* __restrict__ dst,
                          const int* __restrict__ mapping, int* __restrict__ cnt){
  int fi = blockIdx.x*blockDim.x + threadIdx.x;
  if (fi < 32768) cnt[fi] = 0;
  int b = blockIdx.x;
  int xcd = b & 7, idx = b >> 3;
  int graph = xcd*8 + (idx >> 5);
  int i = graph*EPG + (idx & 31)*256 + threadIdx.x;
  int s = src[i];
  if (s < 0) return;
  int ns = mapping[s], nd = mapping[dst[i]];
  if (ns < 0 || nd < 0){ src[i] = -1; }
  else { src[i] = ns; dst[i] = nd; }
}

// z(64x256) -> relu(@L1W+b) -> relu(@L2W+b) -> log_softmax. One block per graph.
__global__ void k_mlp(const float* __restrict__ z, const float* __restrict__ L1W,
                      const float* __restrict__ L1b, const float* __restrict__ L2W,
                      const float* __restrict__ L2b, float* __restrict__ out){
  __shared__ float zr[256];
  __shared__ float h1[128];
  __shared__ float h2[64];
  __shared__ float red[2];
  int g = blockIdx.x, t = threadIdx.x;
  zr[t] = z[g*256 + t];
  __syncthreads();
  if (t < 128){
    float a = L1b[t];
    for (int i = 0; i < 256; i++) a += zr[i]*L1W[i*128 + t];
    h1[t] = fmaxf(a, 0.f);
  }
  __syncthreads();
  if (t < 64){
    float a = L2b[t];
    for (int i = 0; i < 128; i++) a += h1[i]*L2W[i*64 + t];
    h2[t] = fmaxf(a, 0.f);
  }
  __syncthreads();
  if (t == 0){
    float mx = -INFINITY;
    for (int i = 0; i < 64; i++) mx = fmaxf(mx, h2[i]);
    float s = 0.f;
    for (int i = 0; i < 64; i++) s += expf(h2[i] - mx);
    red[0] = mx; red[1] = logf(s);
  }
  __syncthreads();
  if (t < 64) out[g*64 + t] = h2[t] - red[0] - red[1];
}

static void run_level(const float* xin, int fin, const float* W, const float* b,
                      const float* Wp, const float* bp, int nper,
                      int* srcc, int* dstc, int2* csr, int* rowptr, int* cursmap,
                      int* cnt, float* dinvv, float* hp,
                      float* h, float* gout, float* xpool, float* z,
                      bool do_relabel, hipStream_t stream){
  int n = BGR*nper;
  k_gemm8<<<n/8, HID, 0, stream>>>(xin, W, h, fin, nper);
  k_deg_cnt<<<E_TOT/256, 256, 0, stream>>>(srcc, dstc, cnt);
  k_scan<<<BGR, 512, 0, stream>>>(cnt, rowptr, cursmap, dinvv, nper);
  k_csr_fill<<<E_TOT/256, 256, 0, stream>>>(srcc, dstc, dinvv, cursmap, csr);
  k_gcn_gather<<<n/2, 256, 0, stream>>>(h, csr, rowptr, cnt, dinvv, b, Wp, gout, hp, nper);
  k_pool<<<BGR, 256, 0, stream>>>(gout, hp, srcc, dstc, dinvv, bp,
                                  xpool, cursmap, z, nper);
  if (do_relabel) k_relabel<<<E_TOT/256, 256, 0, stream>>>(srcc, dstc, cursmap, cnt);
}

extern "C" void kernel_launch(void* const* d_in, const int* in_sizes, int n_in,
                              void* d_out, int out_size, void* d_ws, size_t ws_size,
                              hipStream_t stream){
  (void)in_sizes; (void)n_in; (void)out_size; (void)ws_size;
  const float* x0  = (const float*)d_in[0];
  const int*   s0  = (const int*)  d_in[1];
  const int*   d0  = (const int*)  d_in[2];
  const float* W1  = (const float*)d_in[3];  const float* b1 = (const float*)d_in[4];
  const float* W2  = (const float*)d_in[5];  const float* b2 = (const float*)d_in[6];
  const float* W3  = (const float*)d_in[7];  const float* b3 = (const float*)d_in[8];
  const float* Wp  = (const float*)d_in[9];  const float* bp = (const float*)d_in[10];
  const float* L1W = (const float*)d_in[11]; const float* L1b = (const float*)d_in[12];
  const float* L2W = (const float*)d_in[13]; const float* L2b = (const float*)d_in[14];
  float* out = (float*)d_out;

  // workspace layout (elements). xp buffers overlay the dead tails of h/gout.
  float* w = (float*)d_ws;
  float* h     = w; w += 32768*HID;          // level XW scratch (level L uses first n*HID)
  float* gout  = w; w += 32768*HID;          // GCN output
  float* xpA   = h    + 16384*HID;           // level-1 pool out (16384x128) — h tail
  float* xpB   = gout + 16384*HID;           // level-2 pool out (8192x128) — gout tail
  float* xpC   = xpA;                        // level-3 pool out (8192x128) — xpA dead
  float* dinvv = w; w += 32768;
  float* hp    = w; w += 32768;
  float* z     = w; w += BGR*256;
  int* cnt     = (int*)w; w += 32768;
  int* rowptr  = (int*)w; w += 32768;
  int* cursmap = (int*)w; w += 32768;        // shared: CSR cursor (early) / mapping (late)
  int* srcc    = (int*)w; w += E_TOT;
  int* dstc    = (int*)w; w += E_TOT;
  int2* csr    = (int2*)w; w += E_TOT*2;

  k_edge_init<<<cdiv(E_TOT,256), 256, 0, stream>>>(s0, d0, srcc, dstc, cnt, z);

  // level 1: 512 nodes/graph -> 256
  run_level(x0, 10, W1, b1, Wp, bp, 512, srcc, dstc, csr, rowptr, cursmap,
            cnt, dinvv, hp, h, gout, xpA, z, true, stream);
  // level 2: 256 -> 128
  run_level(xpA, HID, W2, b2, Wp, bp, 256, srcc, dstc, csr, rowptr, cursmap,
            cnt, dinvv, hp, h, gout, xpB, z, true, stream);
  // level 3: 128 -> 64 (no relabel after final pool)
  run_level(xpB, HID, W3, b3, Wp, bp, 128, srcc, dstc, csr, rowptr, cursmap,
            cnt, dinvv, hp, h, gout, xpC, z, false, stream);

  k_mlp<<<BGR, 256, 0, stream>>>(z, L1W, L1b, L2W, L2b, out);
}

// Round 4
// 366.045 us; speedup vs baseline: 1.3653x; 1.3653x over previous
//
#include <hip/hip_runtime.h>
#include <math.h>

#define BGR 64          // graphs
#define N0 512          // nodes/graph at level 1
#define NDEG 16
#define E_TOT (BGR*N0*NDEG)   // 524288 edge slots, fixed across levels
#define EPG (N0*NDEG)         // 8192 edge slots per graph at every level
#define HID 128

static inline int cdiv(int a, int b){ return (a+b-1)/b; }

// ---- XCD heuristic: blockIdx % 8 -> XCD; graph g pinned to XCD g/8.

__global__ void k_zero_i32(int* p, int n){
  int i = blockIdx.x*blockDim.x + threadIdx.x;
  if (i < n) p[i] = 0;
}

// copy edges into int2 + fused level-1 degree count (cnt must be pre-zeroed)
__global__ void k_edge_init(const int* __restrict__ s0, const int* __restrict__ d0,
                            int2* __restrict__ edges, int* __restrict__ cnt){
  int b = blockIdx.x;
  int xcd = b & 7, idx = b >> 3;
  int graph = xcd*8 + (idx >> 5);
  int i = graph*EPG + (idx & 31)*256 + threadIdx.x;
  int2 e = make_int2(s0[i], d0[i]);
  edges[i] = e;
  atomicAdd(&cnt[e.y], 1);
}

// h = x @ W, 8 nodes per 128-thread block (reuse W across nodes), XCD-pinned
__global__ void k_gemm8(const float* __restrict__ x, const float* __restrict__ W,
                        float* __restrict__ out, int fin, int nper){
  __shared__ float xr[8][HID];
  int b = blockIdx.x;
  int xcd = b & 7, idx = b >> 3, bpg = nper >> 3;
  int graph = xcd*8 + idx / bpg;
  int base = graph*nper + (idx % bpg)*8;
  int f = threadIdx.x;
  #pragma unroll
  for (int nd = 0; nd < 8; nd++) if (f < fin) xr[nd][f] = x[(base+nd)*fin + f];
  __syncthreads();
  float acc[8] = {0,0,0,0,0,0,0,0};
  for (int i = 0; i < fin; i++){
    float wv = W[i*HID + f];
    #pragma unroll
    for (int nd = 0; nd < 8; nd++) acc[nd] += xr[nd][i]*wv;
  }
  #pragma unroll
  for (int nd = 0; nd < 8; nd++) out[(base+nd)*HID + f] = acc[nd];
}

// per-graph exclusive scan of cnt -> rowptr & cursor; fused dinv = rsqrt(cnt+1)
__global__ void k_scan(const int* __restrict__ cnt, int* __restrict__ rowptr,
                       int* __restrict__ cursor, float* __restrict__ dinv, int nper){
  __shared__ int sb[512];
  int g = (blockIdx.x & 7)*8 + (blockIdx.x >> 3);
  int t = threadIdx.x;
  int v = (t < nper) ? cnt[g*nper + t] : 0;
  sb[t] = v; __syncthreads();
  for (int off = 1; off < nper; off <<= 1){
    int add = (t >= off) ? sb[t-off] : 0;
    __syncthreads();
    sb[t] += add;
    __syncthreads();
  }
  if (t < nper){
    int excl = sb[t] - v;
    rowptr[g*nper + t] = g*EPG + excl;
    cursor[g*nper + t] = g*EPG + excl;
    dinv[g*nper + t] = rsqrtf((float)v + 1.0f);   // +1 self-loop
  }
}

// pack each live edge as {src, bitcast(dinv[s]*dinv[d])} into dst's CSR row
__global__ void k_csr_fill(const int2* __restrict__ edges, const float* __restrict__ dinv,
                           int* __restrict__ cursor, int2* __restrict__ csr){
  int b = blockIdx.x;
  int xcd = b & 7, idx = b >> 3;
  int graph = xcd*8 + (idx >> 5);
  int i = graph*EPG + (idx & 31)*256 + threadIdx.x;
  int2 e = edges[i];
  if (e.x >= 0){
    int pos = atomicAdd(&cursor[e.y], 1);
    csr[pos] = make_int2(e.x, __float_as_int(dinv[e.x]*dinv[e.y]));
  }
}

// gather GCN, float4: 32 lanes per node-row, 8 nodes per 256-block, XCD-pinned.
// Fused self-loop + bias + relu and hp[node] = row . Wp
__global__ __launch_bounds__(256) void k_gcn_gather(
    const float4* __restrict__ h4, const int2* __restrict__ csr,
    const int* __restrict__ rowptr, const int* __restrict__ cnt,
    const float* __restrict__ dinv, const float4* __restrict__ bias4,
    const float4* __restrict__ Wp4, float4* __restrict__ out4,
    float* __restrict__ hp, int nper){
  int b = blockIdx.x;
  int xcd = b & 7, idx = b >> 3, bpg = nper >> 3;
  int graph = xcd*8 + idx / bpg;
  int node = graph*nper + (idx % bpg)*8 + (threadIdx.x >> 5);
  int l = threadIdx.x & 31;
  int start = rowptr[node], c = cnt[node];
  float4 acc = make_float4(0.f, 0.f, 0.f, 0.f);
  for (int j = 0; j < c; j++){
    int2 e = csr[start + j];
    float wgt = __int_as_float(e.y);
    float4 hv = h4[e.x*32 + l];
    acc.x += wgt*hv.x; acc.y += wgt*hv.y; acc.z += wgt*hv.z; acc.w += wgt*hv.w;
  }
  float di = dinv[node], dd = di*di;
  float4 hs = h4[node*32 + l];
  float4 bb = bias4[l];
  float4 v;
  v.x = fmaxf(acc.x + hs.x*dd + bb.x, 0.f);
  v.y = fmaxf(acc.y + hs.y*dd + bb.y, 0.f);
  v.z = fmaxf(acc.z + hs.z*dd + bb.z, 0.f);
  v.w = fmaxf(acc.w + hs.w*dd + bb.w, 0.f);
  out4[node*32 + l] = v;
  float4 wp = Wp4[l];
  float contrib = v.x*wp.x + v.y*wp.y + v.z*wp.z + v.w*wp.w;
  #pragma unroll
  for (int off = 16; off; off >>= 1) contrib += __shfl_down(contrib, off, 32);
  if (l == 0) hp[node] = contrib;
}

// node-parallel score: tanh(CSR-gather of hp + self + bp)
__global__ void k_score(const float* __restrict__ hp, const int2* __restrict__ csr,
                        const int* __restrict__ rowptr, const int* __restrict__ cnt,
                        const float* __restrict__ dinv, const float* __restrict__ bp,
                        float* __restrict__ svg, int n){
  int node = blockIdx.x*256 + threadIdx.x;
  if (node >= n) return;
  int start = rowptr[node], c = cnt[node];
  float a = 0.f;
  for (int j = 0; j < c; j++){
    int2 e = csr[start + j];
    a += __int_as_float(e.y) * hp[e.x];
  }
  float di = dinv[node];
  svg[node] = tanhf(a + hp[node]*di*di + bp[0]);
}

// per-graph bitonic sort (512 threads, 1 elem/thread) -> perm, vals, mapping.
// Also zeroes cnt for the next level's degree count.
__global__ __launch_bounds__(512) void k_topk(
    const float* __restrict__ svg, float* __restrict__ vals, int* __restrict__ perm,
    int* __restrict__ mapping, int* __restrict__ cnt, int nper){
  __shared__ float sv[512];
  __shared__ int   si[512];
  int g = (blockIdx.x & 7)*8 + (blockIdx.x >> 3);
  int t = threadIdx.x;
  int k = nper >> 1, gbase = g*nper;
  if (t < nper){
    sv[t] = svg[gbase + t];
    si[t] = t;
    mapping[gbase + t] = -1;
    cnt[gbase + t] = 0;
  }
  __syncthreads();
  for (int kk = 2; kk <= nper; kk <<= 1){
    for (int jj = kk >> 1; jj > 0; jj >>= 1){
      if (t < nper){
        int ixj = t ^ jj;
        if (ixj > t){
          float av = sv[t], bv = sv[ixj];
          int   ai = si[t], bi = si[ixj];
          bool worseA = (av < bv) || (av == bv && ai > bi);
          bool dir = ((t & kk) == 0);
          if (dir ? worseA : !worseA){
            sv[t] = bv; si[t] = bi; sv[ixj] = av; si[ixj] = ai;
          }
        }
      }
      __syncthreads();
    }
  }
  if (t < k){
    vals[g*k + t] = sv[t];
    perm[g*k + t] = si[t];
    mapping[gbase + si[t]] = g*k + t;
  }
}

// pooled rows + per-chunk readout partials. grid = 64*chunks, 32 rows/chunk.
__global__ void k_poolout(const float* __restrict__ gout, const float* __restrict__ vals,
                          const int* __restrict__ perm, float* __restrict__ xpool,
                          float* __restrict__ zmax, float* __restrict__ zsum,
                          int nper, int k, int chunks, int lev_off){
  __shared__ float rmx[128], rsm[128];
  int b = blockIdx.x;
  int xcd = b & 7, idx = b >> 3;
  int graph = xcd*8 + idx / chunks;
  int chunk = idx % chunks;
  int t = threadIdx.x, f = t & 127, jh = t >> 7;
  int gbase = graph*nper;
  float mx = -INFINITY, sm = 0.f;
  for (int j = chunk*32 + jh; j < chunk*32 + 32; j += 2){
    float v = gout[(gbase + perm[graph*k + j])*HID + f] * vals[graph*k + j];
    xpool[(graph*k + j)*HID + f] = v;
    mx = fmaxf(mx, v); sm += v;
  }
  if (jh == 1){ rmx[f] = mx; rsm[f] = sm; }
  __syncthreads();
  if (jh == 0){
    int o = lev_off + (graph*8 + chunk)*128 + f;
    zmax[o] = fmaxf(mx, rmx[f]);
    zsum[o] = sm + rsm[f];
  }
}

// relabel edges for next level; fused next-level degree count (cnt zeroed by k_topk)
__global__ void k_relabel(int2* __restrict__ edges, const int* __restrict__ mapping,
                          int* __restrict__ cnt){
  int b = blockIdx.x;
  int xcd = b & 7, idx = b >> 3;
  int graph = xcd*8 + (idx >> 5);
  int i = graph*EPG + (idx & 31)*256 + threadIdx.x;
  int2 e = edges[i];
  if (e.x < 0) return;
  int ns = mapping[e.x], nd = mapping[e.y];
  if (ns < 0 || nd < 0){ edges[i] = make_int2(-1, 0); }
  else { edges[i] = make_int2(ns, nd); atomicAdd(&cnt[nd], 1); }
}

// finalize readout from zpart + MLP + log_softmax. One block per graph.
__global__ void k_mlp(const float* __restrict__ zmax, const float* __restrict__ zsum,
                      const float* __restrict__ L1W, const float* __restrict__ L1b,
                      const float* __restrict__ L2W, const float* __restrict__ L2b,
                      float* __restrict__ out){
  __shared__ float zr[256];
  __shared__ float h1[128];
  __shared__ float h2[64];
  __shared__ float red[2];
  int g = blockIdx.x, t = threadIdx.x;
  const int S = 64*8*128;
  const int NCH[3] = {8, 4, 2};
  const float KINV[3] = {1.f/256.f, 1.f/128.f, 1.f/64.f};
  if (t < 128){
    float acc = 0.f;
    for (int lev = 0; lev < 3; lev++){
      float m = -INFINITY;
      for (int c = 0; c < NCH[lev]; c++) m = fmaxf(m, zmax[lev*S + (g*8 + c)*128 + t]);
      acc += m;
    }
    zr[t] = acc;
  } else {
    int f = t - 128;
    float acc = 0.f;
    for (int lev = 0; lev < 3; lev++){
      float s = 0.f;
      for (int c = 0; c < NCH[lev]; c++) s += zsum[lev*S + (g*8 + c)*128 + f];
      acc += s * KINV[lev];
    }
    zr[t] = acc;
  }
  __syncthreads();
  if (t < 128){
    float a = L1b[t];
    for (int i = 0; i < 256; i++) a += zr[i]*L1W[i*128 + t];
    h1[t] = fmaxf(a, 0.f);
  }
  __syncthreads();
  if (t < 64){
    float a = L2b[t];
    for (int i = 0; i < 128; i++) a += h1[i]*L2W[i*64 + t];
    h2[t] = fmaxf(a, 0.f);
  }
  __syncthreads();
  if (t == 0){
    float mx = -INFINITY;
    for (int i = 0; i < 64; i++) mx = fmaxf(mx, h2[i]);
    float s = 0.f;
    for (int i = 0; i < 64; i++) s += expf(h2[i] - mx);
    red[0] = mx; red[1] = logf(s);
  }
  __syncthreads();
  if (t < 64) out[g*64 + t] = h2[t] - red[0] - red[1];
}

static void run_level(const float* xin, int fin, const float* W, const float* b,
                      const float* Wp, const float* bp, int nper, int lev,
                      int2* edges, int2* csr, int* rowptr, int* cursmap, int* cnt,
                      float* dinvv, float* hp, float* svg, float* vals, int* perm,
                      float* h, float* gout, float* xpool, float* zmax, float* zsum,
                      bool do_relabel, hipStream_t stream){
  int n = BGR*nper, k = nper >> 1, chunks = k/32;
  k_gemm8<<<n/8, HID, 0, stream>>>(xin, W, h, fin, nper);
  k_scan<<<BGR, 512, 0, stream>>>(cnt, rowptr, cursmap, dinvv, nper);
  k_csr_fill<<<E_TOT/256, 256, 0, stream>>>(edges, dinvv, cursmap, csr);
  k_gcn_gather<<<n/8, 256, 0, stream>>>((const float4*)h, csr, rowptr, cnt, dinvv,
                                        (const float4*)b, (const float4*)Wp,
                                        (float4*)gout, hp, nper);
  k_score<<<cdiv(n,256), 256, 0, stream>>>(hp, csr, rowptr, cnt, dinvv, bp, svg, n);
  k_topk<<<BGR, 512, 0, stream>>>(svg, vals, perm, cursmap, cnt, nper);
  k_poolout<<<BGR*chunks, 256, 0, stream>>>(gout, vals, perm, xpool, zmax, zsum,
                                            nper, k, chunks, lev*64*8*128);
  if (do_relabel) k_relabel<<<E_TOT/256, 256, 0, stream>>>(edges, cursmap, cnt);
}

extern "C" void kernel_launch(void* const* d_in, const int* in_sizes, int n_in,
                              void* d_out, int out_size, void* d_ws, size_t ws_size,
                              hipStream_t stream){
  (void)in_sizes; (void)n_in; (void)out_size; (void)ws_size;
  const float* x0  = (const float*)d_in[0];
  const int*   s0  = (const int*)  d_in[1];
  const int*   d0  = (const int*)  d_in[2];
  const float* W1  = (const float*)d_in[3];  const float* b1 = (const float*)d_in[4];
  const float* W2  = (const float*)d_in[5];  const float* b2 = (const float*)d_in[6];
  const float* W3  = (const float*)d_in[7];  const float* b3 = (const float*)d_in[8];
  const float* Wp  = (const float*)d_in[9];  const float* bp = (const float*)d_in[10];
  const float* L1W = (const float*)d_in[11]; const float* L1b = (const float*)d_in[12];
  const float* L2W = (const float*)d_in[13]; const float* L2b = (const float*)d_in[14];
  float* out = (float*)d_out;

  // workspace layout (elements). xp buffers overlay the dead tails of h/gout.
  float* w = (float*)d_ws;
  float* h     = w; w += 32768*HID;
  float* gout  = w; w += 32768*HID;
  float* xpA   = h    + 16384*HID;           // level-1 pool out (16384 rows) — h tail
  float* xpB   = gout + 16384*HID;           // level-2 pool out (8192 rows) — gout tail
  float* xpC   = xpA;                        // level-3 pool out — xpA dead by then
  float* dinvv = w; w += 32768;
  float* hp    = w; w += 32768;
  float* svg   = w; w += 32768;
  float* vals  = w; w += 16384;
  float* zmax  = w; w += 3*64*8*128;
  float* zsum  = w; w += 3*64*8*128;
  int* cnt     = (int*)w; w += 32768;
  int* rowptr  = (int*)w; w += 32768;
  int* cursmap = (int*)w; w += 32768;        // CSR cursor (early) / mapping (late)
  int* perm    = (int*)w; w += 16384;
  int2* edges  = (int2*)w; w += E_TOT*2;
  int2* csr    = (int2*)w; w += E_TOT*2;

  k_zero_i32<<<128, 256, 0, stream>>>(cnt, 32768);
  k_edge_init<<<E_TOT/256, 256, 0, stream>>>(s0, d0, edges, cnt);

  // level 1: 512 nodes/graph -> 256
  run_level(x0, 10, W1, b1, Wp, bp, 512, 0, edges, csr, rowptr, cursmap, cnt,
            dinvv, hp, svg, vals, perm, h, gout, xpA, zmax, zsum, true, stream);
  // level 2: 256 -> 128
  run_level(xpA, HID, W2, b2, Wp, bp, 256, 1, edges, csr, rowptr, cursmap, cnt,
            dinvv, hp, svg, vals, perm, h, gout, xpB, zmax, zsum, true, stream);
  // level 3: 128 -> 64 (no relabel after final pool)
  run_level(xpB, HID, W3, b3, Wp, bp, 128, 2, edges, csr, rowptr, cursmap, cnt,
            dinvv, hp, svg, vals, perm, h, gout, xpC, zmax, zsum, false, stream);

  k_mlp<<<BGR, 256, 0, stream>>>(zmax, zsum, L1W, L1b, L2W, L2b, out);
}

// Round 5
// 285.618 us; speedup vs baseline: 1.7498x; 1.2816x over previous
//
#include <hip/hip_runtime.h>
#include <math.h>

#define BGR 64          // graphs
#define N0 512          // nodes/graph at level 1
#define NDEG 16
#define E_TOT (BGR*N0*NDEG)   // 524288 edge slots, fixed across levels
#define EPG (N0*NDEG)         // 8192 edge slots per graph at every level
#define EIT (EPG/512)         // 16 edge iterations per 512-thread block
#define HID 128

// ---- XCD heuristic: blockIdx % 8 -> XCD; graph g pinned to XCD g/8.

__global__ void k_zero(int* __restrict__ cnt, float* __restrict__ z){
  int i = blockIdx.x*256 + threadIdx.x;    // grid = 128 blocks -> 32768
  cnt[i] = 0;
  if (i < BGR*256) z[i] = 0.f;
}

// copy edges into int2 + fused level-1 degree count (cnt pre-zeroed)
__global__ void k_edge_init(const int* __restrict__ s0, const int* __restrict__ d0,
                            int2* __restrict__ edges, int* __restrict__ cnt){
  int b = blockIdx.x;
  int xcd = b & 7, idx = b >> 3;
  int graph = xcd*8 + (idx >> 5);
  int i = graph*EPG + (idx & 31)*256 + threadIdx.x;
  int2 e = make_int2(s0[i], d0[i]);
  edges[i] = e;
  atomicAdd(&cnt[e.y], 1);
}

// level-1 topology: per-graph scan of cnt -> rowptr/dinv + CSR fill (LDS cursors)
__global__ __launch_bounds__(512) void k_csr0(
    const int2* __restrict__ edges, const int* __restrict__ cnt,
    int* __restrict__ rowptr, float* __restrict__ dinv, int2* __restrict__ csr){
  __shared__ int   sb[512];
  __shared__ int   cur[512];
  __shared__ float dl[512];
  int g = (blockIdx.x & 7)*8 + (blockIdx.x >> 3);
  int t = threadIdx.x;
  int gbase = g*N0, ebase = g*EPG;
  int vdeg = cnt[gbase + t];
  sb[t] = vdeg; __syncthreads();
  for (int off = 1; off < 512; off <<= 1){
    int add = (t >= off) ? sb[t-off] : 0;
    __syncthreads(); sb[t] += add; __syncthreads();
  }
  int excl = sb[t] - vdeg;
  rowptr[gbase + t] = ebase + excl;
  cur[t] = excl;
  float dv = rsqrtf((float)vdeg + 1.f);
  dl[t] = dv;
  dinv[gbase + t] = dv;
  __syncthreads();
  #pragma unroll
  for (int it = 0; it < EIT; it++){
    int2 e = edges[ebase + it*512 + t];
    int sl = e.x - gbase, dc = e.y - gbase;
    int pos = atomicAdd(&cur[dc], 1);
    csr[ebase + pos] = make_int2(e.x, __float_as_int(dl[sl]*dl[dc]));
  }
}

// h = x @ W, 8 nodes per 128-thread block (reuse W across nodes), XCD-pinned
__global__ void k_gemm8(const float* __restrict__ x, const float* __restrict__ W,
                        float* __restrict__ out, int fin, int nper){
  __shared__ float xr[8][HID];
  int b = blockIdx.x;
  int xcd = b & 7, idx = b >> 3, bpg = nper >> 3;
  int graph = xcd*8 + idx / bpg;
  int base = graph*nper + (idx % bpg)*8;
  int f = threadIdx.x;
  #pragma unroll
  for (int nd = 0; nd < 8; nd++) if (f < fin) xr[nd][f] = x[(base+nd)*fin + f];
  __syncthreads();
  float acc[8] = {0,0,0,0,0,0,0,0};
  for (int i = 0; i < fin; i++){
    float wv = W[i*HID + f];
    #pragma unroll
    for (int nd = 0; nd < 8; nd++) acc[nd] += xr[nd][i]*wv;
  }
  #pragma unroll
  for (int nd = 0; nd < 8; nd++) out[(base+nd)*HID + f] = acc[nd];
}

// gather GCN, float4: 32 lanes per node-row, 8 nodes per 256-block, XCD-pinned.
// Fused self-loop + bias + relu and hp[node] = row . Wp
__global__ __launch_bounds__(256) void k_gcn_gather(
    const float4* __restrict__ h4, const int2* __restrict__ csr,
    const int* __restrict__ rowptr, const int* __restrict__ cnt,
    const float* __restrict__ dinv, const float4* __restrict__ bias4,
    const float4* __restrict__ Wp4, float4* __restrict__ out4,
    float* __restrict__ hp, int nper){
  int b = blockIdx.x;
  int xcd = b & 7, idx = b >> 3, bpg = nper >> 3;
  int graph = xcd*8 + idx / bpg;
  int node = graph*nper + (idx % bpg)*8 + (threadIdx.x >> 5);
  int l = threadIdx.x & 31;
  int start = rowptr[node], c = cnt[node];
  float4 acc = make_float4(0.f, 0.f, 0.f, 0.f);
  for (int j = 0; j < c; j++){
    int2 e = csr[start + j];
    float wgt = __int_as_float(e.y);
    float4 hv = h4[e.x*32 + l];
    acc.x += wgt*hv.x; acc.y += wgt*hv.y; acc.z += wgt*hv.z; acc.w += wgt*hv.w;
  }
  float di = dinv[node], dd = di*di;
  float4 hs = h4[node*32 + l];
  float4 bb = bias4[l];
  float4 v;
  v.x = fmaxf(acc.x + hs.x*dd + bb.x, 0.f);
  v.y = fmaxf(acc.y + hs.y*dd + bb.y, 0.f);
  v.z = fmaxf(acc.z + hs.z*dd + bb.z, 0.f);
  v.w = fmaxf(acc.w + hs.w*dd + bb.w, 0.f);
  out4[node*32 + l] = v;
  float4 wp = Wp4[l];
  float contrib = v.x*wp.x + v.y*wp.y + v.z*wp.z + v.w*wp.w;
  #pragma unroll
  for (int off = 16; off; off >>= 1) contrib += __shfl_down(contrib, off, 32);
  if (l == 0) hp[node] = contrib;
}

// Per-graph mega: score -> hybrid shfl/LDS bitonic top-k -> pooled rows +
// fused readout (z +=) -> relabel (register-buffered) -> next-level degree,
// scan, dinv, rowptr, CSR fill. One block per graph, XCD-pinned.
__global__ __launch_bounds__(512) void k_mega(
    const float4* __restrict__ gout4, const float* __restrict__ hp,
    int2* __restrict__ csr, int* __restrict__ rowptr, int* __restrict__ cnt,
    float* __restrict__ dinv, const float* __restrict__ bp,
    int2* __restrict__ edges, float4* __restrict__ xpool4,
    float* __restrict__ z, int nper, int lastlev){
  __shared__ float sv[512];
  __shared__ int   si[512];
  __shared__ float hpl[512];
  __shared__ int   map[512];
  __shared__ int   sb[512];
  __shared__ int   cur[256];
  __shared__ float dl[256];
  __shared__ float4 pmx[16][32];
  __shared__ float4 psm[16][32];
  int g = (blockIdx.x & 7)*8 + (blockIdx.x >> 3);
  int t = threadIdx.x;
  int k = nper >> 1;
  int gbase = g*nper, ebase = g*EPG, gb2 = g*k;
  bool act = t < nper;
  // ---- score: tanh(CSR-gather over LDS hp + self + bp) ----
  if (act) hpl[t] = hp[gbase + t];
  __syncthreads();
  float v = 0.f; int idx = t;
  if (act){
    int start = rowptr[gbase + t], c = cnt[gbase + t];
    float a = 0.f;
    for (int j = 0; j < c; j++){
      int2 e = csr[start + j];
      a += __int_as_float(e.y) * hpl[e.x - gbase];
    }
    float di = dinv[gbase + t];
    v = tanhf(a + hpl[t]*di*di + bp[0]);
  }
  // ---- bitonic sort desc (ties: lower index). jj<64 in-register via shfl ----
  for (int kk = 2; kk <= nper; kk <<= 1){
    for (int jj = kk >> 1; jj > 0; jj >>= 1){
      if (jj >= 64){
        if (act){ sv[t] = v; si[t] = idx; }
        __syncthreads();
        if (act){
          int p = t ^ jj;
          float pv = sv[p]; int pi = si[p];
          bool amLower = (t & jj) == 0;
          bool dirDesc = (t & kk) == 0;
          bool betterMine = (v > pv) || (v == pv && idx < pi);
          if ((amLower == dirDesc) != betterMine){ v = pv; idx = pi; }
        }
        __syncthreads();
      } else if (act){
        float pv = __shfl_xor(v, jj);
        int   pi = __shfl_xor(idx, jj);
        bool amLower = (t & jj) == 0;
        bool dirDesc = (t & kk) == 0;
        bool betterMine = (v > pv) || (v == pv && idx < pi);
        if ((amLower == dirDesc) != betterMine){ v = pv; idx = pi; }
      }
    }
  }
  if (act){ sv[t] = v; si[t] = idx; }
  __syncthreads();
  // ---- pooled rows + readout partials (float4) ----
  int l = t & 31, j0 = t >> 5;
  float4 mx = make_float4(-INFINITY,-INFINITY,-INFINITY,-INFINITY);
  float4 sm = make_float4(0.f,0.f,0.f,0.f);
  for (int j = j0; j < k; j += 16){
    float val = sv[j]; int row = si[j];
    float4 hv = gout4[(gbase + row)*32 + l];
    float4 o = make_float4(hv.x*val, hv.y*val, hv.z*val, hv.w*val);
    xpool4[(gb2 + j)*32 + l] = o;
    mx.x = fmaxf(mx.x, o.x); mx.y = fmaxf(mx.y, o.y);
    mx.z = fmaxf(mx.z, o.z); mx.w = fmaxf(mx.w, o.w);
    sm.x += o.x; sm.y += o.y; sm.z += o.z; sm.w += o.w;
  }
  pmx[j0][l] = mx; psm[j0][l] = sm;
  __syncthreads();
  if (t < 32){
    float4 M = pmx[0][t], S = psm[0][t];
    #pragma unroll
    for (int q = 1; q < 16; q++){
      float4 m2 = pmx[q][t], s2 = psm[q][t];
      M.x = fmaxf(M.x, m2.x); M.y = fmaxf(M.y, m2.y);
      M.z = fmaxf(M.z, m2.z); M.w = fmaxf(M.w, m2.w);
      S.x += s2.x; S.y += s2.y; S.z += s2.z; S.w += s2.w;
    }
    float ki = 1.f/(float)k;
    float* zp = z + g*256;
    zp[t*4+0] += M.x; zp[t*4+1] += M.y; zp[t*4+2] += M.z; zp[t*4+3] += M.w;
    zp[128+t*4+0] += S.x*ki; zp[128+t*4+1] += S.y*ki;
    zp[128+t*4+2] += S.z*ki; zp[128+t*4+3] += S.w*ki;
  }
  if (lastlev) return;
  // ---- mapping ----
  if (act) map[t] = -1;
  if (t < k) sb[t] = 0;
  __syncthreads();
  if (t < k) map[si[t]] = t;
  __syncthreads();
  // ---- relabel (register-buffered) + next degree count ----
  int2 ebuf[EIT];
  #pragma unroll
  for (int it = 0; it < EIT; it++){
    int i = ebase + it*512 + t;
    int2 e = edges[i];
    int2 ne = make_int2(-1, 0);
    if (e.x >= 0){
      int ns = map[e.x - gbase], nd = map[e.y - gbase];
      if (ns >= 0 && nd >= 0){
        ne = make_int2(gb2 + ns, gb2 + nd);
        atomicAdd(&sb[nd], 1);
      }
    }
    ebuf[it] = ne;
    edges[i] = ne;
  }
  __syncthreads();
  // ---- scan new degrees (k elems) -> rowptr/cnt/dinv/cursor ----
  int vdeg = (t < k) ? sb[t] : 0;
  for (int off = 1; off < k; off <<= 1){
    int add = (t >= off && t < k) ? sb[t-off] : 0;
    __syncthreads();
    if (t < k) sb[t] += add;
    __syncthreads();
  }
  if (t < k){
    int excl = sb[t] - vdeg;
    rowptr[gb2 + t] = ebase + excl;
    cnt[gb2 + t] = vdeg;
    cur[t] = excl;
    float dv = rsqrtf((float)vdeg + 1.f);
    dl[t] = dv;
    dinv[gb2 + t] = dv;
  }
  __syncthreads();
  // ---- next-level CSR fill from register buffer ----
  #pragma unroll
  for (int it = 0; it < EIT; it++){
    int2 e = ebuf[it];
    if (e.x >= 0){
      int sl = e.x - gb2, dc = e.y - gb2;
      int pos = atomicAdd(&cur[dc], 1);
      csr[ebase + pos] = make_int2(e.x, __float_as_int(dl[sl]*dl[dc]));
    }
  }
}

// z(64x256) -> relu(@L1W+b) -> relu(@L2W+b) -> log_softmax. One block per graph.
__global__ void k_mlp(const float* __restrict__ z, const float* __restrict__ L1W,
                      const float* __restrict__ L1b, const float* __restrict__ L2W,
                      const float* __restrict__ L2b, float* __restrict__ out){
  __shared__ float zr[256];
  __shared__ float h1[128];
  __shared__ float h2[64];
  __shared__ float red[2];
  int g = blockIdx.x, t = threadIdx.x;
  zr[t] = z[g*256 + t];
  __syncthreads();
  if (t < 128){
    float a = L1b[t];
    for (int i = 0; i < 256; i++) a += zr[i]*L1W[i*128 + t];
    h1[t] = fmaxf(a, 0.f);
  }
  __syncthreads();
  if (t < 64){
    float a = L2b[t];
    for (int i = 0; i < 128; i++) a += h1[i]*L2W[i*64 + t];
    h2[t] = fmaxf(a, 0.f);
  }
  __syncthreads();
  if (t == 0){
    float mx = -INFINITY;
    for (int i = 0; i < 64; i++) mx = fmaxf(mx, h2[i]);
    float s = 0.f;
    for (int i = 0; i < 64; i++) s += expf(h2[i] - mx);
    red[0] = mx; red[1] = logf(s);
  }
  __syncthreads();
  if (t < 64) out[g*64 + t] = h2[t] - red[0] - red[1];
}

extern "C" void kernel_launch(void* const* d_in, const int* in_sizes, int n_in,
                              void* d_out, int out_size, void* d_ws, size_t ws_size,
                              hipStream_t stream){
  (void)in_sizes; (void)n_in; (void)out_size; (void)ws_size;
  const float* x0  = (const float*)d_in[0];
  const int*   s0  = (const int*)  d_in[1];
  const int*   d0  = (const int*)  d_in[2];
  const float* W1  = (const float*)d_in[3];  const float* b1 = (const float*)d_in[4];
  const float* W2  = (const float*)d_in[5];  const float* b2 = (const float*)d_in[6];
  const float* W3  = (const float*)d_in[7];  const float* b3 = (const float*)d_in[8];
  const float* Wp  = (const float*)d_in[9];  const float* bp = (const float*)d_in[10];
  const float* L1W = (const float*)d_in[11]; const float* L1b = (const float*)d_in[12];
  const float* L2W = (const float*)d_in[13]; const float* L2b = (const float*)d_in[14];
  float* out = (float*)d_out;

  // workspace layout (elements). xp buffers overlay dead tails of h/gout.
  float* w = (float*)d_ws;
  float* h     = w; w += 32768*HID;
  float* gout  = w; w += 32768*HID;
  float* xpA   = h    + 16384*HID;           // level-1 pool out — h tail
  float* xpB   = gout + 16384*HID;           // level-2 pool out — gout tail
  float* xpC   = xpA;                        // level-3 pool out — xpA dead by then
  float* dinvv = w; w += 32768;
  float* hp    = w; w += 32768;
  float* z     = w; w += BGR*256;
  int* cnt     = (int*)w; w += 32768;
  int* rowptr  = (int*)w; w += 32768;
  int2* edges  = (int2*)w; w += E_TOT*2;
  int2* csr    = (int2*)w; w += E_TOT*2;

  k_zero<<<128, 256, 0, stream>>>(cnt, z);
  k_edge_init<<<E_TOT/256, 256, 0, stream>>>(s0, d0, edges, cnt);
  k_csr0<<<BGR, 512, 0, stream>>>(edges, cnt, rowptr, dinvv, csr);

  // level 1: 512 -> 256
  k_gemm8<<<32768/8, HID, 0, stream>>>(x0, W1, h, 10, 512);
  k_gcn_gather<<<32768/8, 256, 0, stream>>>((const float4*)h, csr, rowptr, cnt, dinvv,
                                            (const float4*)b1, (const float4*)Wp,
                                            (float4*)gout, hp, 512);
  k_mega<<<BGR, 512, 0, stream>>>((const float4*)gout, hp, csr, rowptr, cnt, dinvv,
                                  bp, edges, (float4*)xpA, z, 512, 0);
  // level 2: 256 -> 128
  k_gemm8<<<16384/8, HID, 0, stream>>>(xpA, W2, h, HID, 256);
  k_gcn_gather<<<16384/8, 256, 0, stream>>>((const float4*)h, csr, rowptr, cnt, dinvv,
                                            (const float4*)b2, (const float4*)Wp,
                                            (float4*)gout, hp, 256);
  k_mega<<<BGR, 512, 0, stream>>>((const float4*)gout, hp, csr, rowptr, cnt, dinvv,
                                  bp, edges, (float4*)xpB, z, 256, 0);
  // level 3: 128 -> 64
  k_gemm8<<<8192/8, HID, 0, stream>>>(xpB, W3, h, HID, 128);
  k_gcn_gather<<<8192/8, 256, 0, stream>>>((const float4*)h, csr, rowptr, cnt, dinvv,
                                           (const float4*)b3, (const float4*)Wp,
                                           (float4*)gout, hp, 128);
  k_mega<<<BGR, 512, 0, stream>>>((const float4*)gout, hp, csr, rowptr, cnt, dinvv,
                                  bp, edges, (float4*)xpC, z, 128, 1);

  k_mlp<<<BGR, 256, 0, stream>>>(z, L1W, L1b, L2W, L2b, out);
}

// Round 6
// 254.463 us; speedup vs baseline: 1.9640x; 1.1224x over previous
//
#include <hip/hip_runtime.h>
#include <math.h>

#define BGR 64          // graphs
#define N0 512          // nodes/graph at level 1
#define NDEG 16
#define E_TOT (BGR*N0*NDEG)   // 524288 edge slots, fixed across levels
#define EPG (N0*NDEG)         // 8192 edge slots per graph at every level
#define EIT (EPG/512)         // 16 edge iterations per 512-thread block
#define HID 128

// ---- XCD heuristic: blockIdx % 8 -> XCD; graph g pinned to XCD g/8.

// Per-graph level-1 topology, fully fused: edge copy + degree (LDS atomics) +
// scan + dinv + CSR fill (edges register-buffered). Also zeroes z.
__global__ __launch_bounds__(512) void k_topo0(
    const int* __restrict__ s0, const int* __restrict__ d0,
    int2* __restrict__ edges, int* __restrict__ cnt, int* __restrict__ rowptr,
    float* __restrict__ dinv, int2* __restrict__ csr, float* __restrict__ z){
  __shared__ int   deg[512];
  __shared__ int   sb[512];
  __shared__ int   cur[512];
  __shared__ float dl[512];
  int g = (blockIdx.x & 7)*8 + (blockIdx.x >> 3);
  int t = threadIdx.x;
  int gbase = g*N0, ebase = g*EPG;
  deg[t] = 0;
  if (t < 256) z[g*256 + t] = 0.f;
  __syncthreads();
  int2 ebuf[EIT];
  #pragma unroll
  for (int it = 0; it < EIT; it++){
    int i = ebase + it*512 + t;
    int2 e = make_int2(s0[i], d0[i]);
    ebuf[it] = e;
    edges[i] = e;
    atomicAdd(&deg[e.y - gbase], 1);
  }
  __syncthreads();
  int vdeg = deg[t];
  sb[t] = vdeg; __syncthreads();
  for (int off = 1; off < 512; off <<= 1){
    int add = (t >= off) ? sb[t-off] : 0;
    __syncthreads(); sb[t] += add; __syncthreads();
  }
  int excl = sb[t] - vdeg;
  rowptr[gbase + t] = ebase + excl;
  cnt[gbase + t] = vdeg;
  cur[t] = excl;
  float dv = rsqrtf((float)vdeg + 1.f);
  dl[t] = dv;
  dinv[gbase + t] = dv;
  __syncthreads();
  #pragma unroll
  for (int it = 0; it < EIT; it++){
    int2 e = ebuf[it];
    int sl = e.x - gbase, dc = e.y - gbase;
    int pos = atomicAdd(&cur[dc], 1);
    csr[ebase + pos] = make_int2(e.x, __float_as_int(dl[sl]*dl[dc]));
  }
}

// Level-1 fused GEMM+gather: block = (graph, feature-quarter). Computes the
// 512x32 h-slice in LDS (64 KB dynamic) from x (fin=10), then gathers
// neighbors from LDS. Writes gout quarter + hp quarter-partial.
__global__ __launch_bounds__(512) void k_l1_fused(
    const float* __restrict__ x, const float* __restrict__ W1,
    const int2* __restrict__ csr, const int* __restrict__ rowptr,
    const int* __restrict__ cnt, const float* __restrict__ dinv,
    const float* __restrict__ b1, const float* __restrict__ Wp,
    float4* __restrict__ gout4, float* __restrict__ hp_part){
  extern __shared__ float hl[];   // 512 nodes x 32 feats = 64 KB
  int b = blockIdx.x;
  int xcd = b & 7, idx = b >> 3;
  int graph = xcd*8 + (idx >> 2);
  int qf = idx & 3;
  int t = threadIdx.x;
  int gbase = graph*N0;
  // phase A: hl[n][f'] = sum_k x[n][k] * W1[k][qf*32+f']
  int fp = t & 31;
  int f = qf*32 + fp;
  float wcol[10];
  #pragma unroll
  for (int k = 0; k < 10; k++) wcol[k] = W1[k*HID + f];
  for (int n = t >> 5; n < N0; n += 16){
    const float* xr = x + (gbase + n)*10;
    float acc = 0.f;
    #pragma unroll
    for (int k = 0; k < 10; k++) acc += xr[k]*wcol[k];
    hl[n*32 + fp] = acc;
  }
  __syncthreads();
  // phase B: gather from LDS. 64 node-groups x 8 lanes (float4 per lane).
  const float4* hl4 = (const float4*)hl;
  int l = t & 7, grp = t >> 3;
  float4 bb = ((const float4*)b1)[qf*8 + l];
  float4 wp = ((const float4*)Wp)[qf*8 + l];
  for (int nl = grp; nl < N0; nl += 64){
    int node = gbase + nl;
    int start = rowptr[node], c = cnt[node];
    float4 acc = make_float4(0.f,0.f,0.f,0.f);
    for (int j = 0; j < c; j++){
      int2 e = csr[start + j];
      float wgt = __int_as_float(e.y);
      float4 hv = hl4[(e.x - gbase)*8 + l];
      acc.x += wgt*hv.x; acc.y += wgt*hv.y; acc.z += wgt*hv.z; acc.w += wgt*hv.w;
    }
    float di = dinv[node], dd = di*di;
    float4 hs = hl4[nl*8 + l];
    float4 v;
    v.x = fmaxf(acc.x + hs.x*dd + bb.x, 0.f);
    v.y = fmaxf(acc.y + hs.y*dd + bb.y, 0.f);
    v.z = fmaxf(acc.z + hs.z*dd + bb.z, 0.f);
    v.w = fmaxf(acc.w + hs.w*dd + bb.w, 0.f);
    gout4[node*32 + qf*8 + l] = v;
    float contrib = v.x*wp.x + v.y*wp.y + v.z*wp.z + v.w*wp.w;
    #pragma unroll
    for (int off = 4; off; off >>= 1) contrib += __shfl_down(contrib, off, 8);
    if (l == 0) hp_part[qf*32768 + node] = contrib;
  }
}

// h = x @ W, 8 nodes per 128-thread block (levels 2/3), XCD-pinned
__global__ void k_gemm8(const float* __restrict__ x, const float* __restrict__ W,
                        float* __restrict__ out, int fin, int nper){
  __shared__ float xr[8][HID];
  int b = blockIdx.x;
  int xcd = b & 7, idx = b >> 3, bpg = nper >> 3;
  int graph = xcd*8 + idx / bpg;
  int base = graph*nper + (idx % bpg)*8;
  int f = threadIdx.x;
  #pragma unroll
  for (int nd = 0; nd < 8; nd++) if (f < fin) xr[nd][f] = x[(base+nd)*fin + f];
  __syncthreads();
  float acc[8] = {0,0,0,0,0,0,0,0};
  for (int i = 0; i < fin; i++){
    float wv = W[i*HID + f];
    #pragma unroll
    for (int nd = 0; nd < 8; nd++) acc[nd] += xr[nd][i]*wv;
  }
  #pragma unroll
  for (int nd = 0; nd < 8; nd++) out[(base+nd)*HID + f] = acc[nd];
}

// gather GCN (levels 2/3), float4: 32 lanes per node-row, 8 nodes per block.
__global__ __launch_bounds__(256) void k_gcn_gather(
    const float4* __restrict__ h4, const int2* __restrict__ csr,
    const int* __restrict__ rowptr, const int* __restrict__ cnt,
    const float* __restrict__ dinv, const float4* __restrict__ bias4,
    const float4* __restrict__ Wp4, float4* __restrict__ out4,
    float* __restrict__ hp, int nper){
  int b = blockIdx.x;
  int xcd = b & 7, idx = b >> 3, bpg = nper >> 3;
  int graph = xcd*8 + idx / bpg;
  int node = graph*nper + (idx % bpg)*8 + (threadIdx.x >> 5);
  int l = threadIdx.x & 31;
  int start = rowptr[node], c = cnt[node];
  float4 acc = make_float4(0.f, 0.f, 0.f, 0.f);
  for (int j = 0; j < c; j++){
    int2 e = csr[start + j];
    float wgt = __int_as_float(e.y);
    float4 hv = h4[e.x*32 + l];
    acc.x += wgt*hv.x; acc.y += wgt*hv.y; acc.z += wgt*hv.z; acc.w += wgt*hv.w;
  }
  float di = dinv[node], dd = di*di;
  float4 hs = h4[node*32 + l];
  float4 bb = bias4[l];
  float4 v;
  v.x = fmaxf(acc.x + hs.x*dd + bb.x, 0.f);
  v.y = fmaxf(acc.y + hs.y*dd + bb.y, 0.f);
  v.z = fmaxf(acc.z + hs.z*dd + bb.z, 0.f);
  v.w = fmaxf(acc.w + hs.w*dd + bb.w, 0.f);
  out4[node*32 + l] = v;
  float4 wp = Wp4[l];
  float contrib = v.x*wp.x + v.y*wp.y + v.z*wp.z + v.w*wp.w;
  #pragma unroll
  for (int off = 16; off; off >>= 1) contrib += __shfl_down(contrib, off, 32);
  if (l == 0) hp[node] = contrib;
}

// Per-graph mega: score -> hybrid shfl/LDS bitonic top-k -> pooled rows +
// fused readout -> relabel + next-level topology. On the last level, runs the
// readout finalize + MLP + log_softmax instead (z kept in LDS).
__global__ __launch_bounds__(512) void k_mega(
    const float4* __restrict__ gout4, const float* __restrict__ hp,
    const float* __restrict__ hp_part, int l1flag,
    int2* __restrict__ csr, int* __restrict__ rowptr, int* __restrict__ cnt,
    float* __restrict__ dinv, const float* __restrict__ bp,
    int2* __restrict__ edges, float4* __restrict__ xpool4,
    float* __restrict__ z, int nper, int lastlev,
    const float* __restrict__ L1W, const float* __restrict__ L1b,
    const float* __restrict__ L2W, const float* __restrict__ L2b,
    float* __restrict__ out){
  __shared__ float sv[512];
  __shared__ int   si[512];
  __shared__ float hpl[512];
  __shared__ int   map[512];
  __shared__ int   sb[512];
  __shared__ int   cur[256];
  __shared__ float dl[256];
  __shared__ float4 pmx[16][32];
  __shared__ float4 psm[16][32];
  __shared__ float zr[256];
  __shared__ float h1[128];
  __shared__ float h2[64];
  __shared__ float red[2];
  int g = (blockIdx.x & 7)*8 + (blockIdx.x >> 3);
  int t = threadIdx.x;
  int k = nper >> 1;
  int gbase = g*nper, ebase = g*EPG, gb2 = g*k;
  bool act = t < nper;
  // ---- score ----
  if (act){
    int node = gbase + t;
    hpl[t] = l1flag ? (hp_part[node] + hp_part[32768 + node] +
                       hp_part[65536 + node] + hp_part[98304 + node])
                    : hp[node];
  }
  __syncthreads();
  float v = 0.f; int idx = t;
  if (act){
    int start = rowptr[gbase + t], c = cnt[gbase + t];
    float a = 0.f;
    for (int j = 0; j < c; j++){
      int2 e = csr[start + j];
      a += __int_as_float(e.y) * hpl[e.x - gbase];
    }
    float di = dinv[gbase + t];
    v = tanhf(a + hpl[t]*di*di + bp[0]);
  }
  // ---- bitonic sort desc (ties: lower index). jj<64 via shfl ----
  for (int kk = 2; kk <= nper; kk <<= 1){
    for (int jj = kk >> 1; jj > 0; jj >>= 1){
      if (jj >= 64){
        if (act){ sv[t] = v; si[t] = idx; }
        __syncthreads();
        if (act){
          int p = t ^ jj;
          float pv = sv[p]; int pi = si[p];
          bool amLower = (t & jj) == 0;
          bool dirDesc = (t & kk) == 0;
          bool betterMine = (v > pv) || (v == pv && idx < pi);
          if ((amLower == dirDesc) != betterMine){ v = pv; idx = pi; }
        }
        __syncthreads();
      } else if (act){
        float pv = __shfl_xor(v, jj);
        int   pi = __shfl_xor(idx, jj);
        bool amLower = (t & jj) == 0;
        bool dirDesc = (t & kk) == 0;
        bool betterMine = (v > pv) || (v == pv && idx < pi);
        if ((amLower == dirDesc) != betterMine){ v = pv; idx = pi; }
      }
    }
  }
  if (act){ sv[t] = v; si[t] = idx; }
  __syncthreads();
  // ---- pooled rows + readout partials ----
  int l = t & 31, j0 = t >> 5;
  float4 mx = make_float4(-INFINITY,-INFINITY,-INFINITY,-INFINITY);
  float4 sm = make_float4(0.f,0.f,0.f,0.f);
  for (int j = j0; j < k; j += 16){
    float val = sv[j]; int row = si[j];
    float4 hv = gout4[(gbase + row)*32 + l];
    float4 o = make_float4(hv.x*val, hv.y*val, hv.z*val, hv.w*val);
    xpool4[(gb2 + j)*32 + l] = o;
    mx.x = fmaxf(mx.x, o.x); mx.y = fmaxf(mx.y, o.y);
    mx.z = fmaxf(mx.z, o.z); mx.w = fmaxf(mx.w, o.w);
    sm.x += o.x; sm.y += o.y; sm.z += o.z; sm.w += o.w;
  }
  pmx[j0][l] = mx; psm[j0][l] = sm;
  __syncthreads();
  if (t < 32){
    float4 M = pmx[0][t], S = psm[0][t];
    #pragma unroll
    for (int q = 1; q < 16; q++){
      float4 m2 = pmx[q][t], s2 = psm[q][t];
      M.x = fmaxf(M.x, m2.x); M.y = fmaxf(M.y, m2.y);
      M.z = fmaxf(M.z, m2.z); M.w = fmaxf(M.w, m2.w);
      S.x += s2.x; S.y += s2.y; S.z += s2.z; S.w += s2.w;
    }
    float ki = 1.f/(float)k;
    float* zp = z + g*256;
    if (!lastlev){
      zp[t*4+0] += M.x; zp[t*4+1] += M.y; zp[t*4+2] += M.z; zp[t*4+3] += M.w;
      zp[128+t*4+0] += S.x*ki; zp[128+t*4+1] += S.y*ki;
      zp[128+t*4+2] += S.z*ki; zp[128+t*4+3] += S.w*ki;
    } else {
      zr[t*4+0] = zp[t*4+0] + M.x; zr[t*4+1] = zp[t*4+1] + M.y;
      zr[t*4+2] = zp[t*4+2] + M.z; zr[t*4+3] = zp[t*4+3] + M.w;
      zr[128+t*4+0] = zp[128+t*4+0] + S.x*ki;
      zr[128+t*4+1] = zp[128+t*4+1] + S.y*ki;
      zr[128+t*4+2] = zp[128+t*4+2] + S.z*ki;
      zr[128+t*4+3] = zp[128+t*4+3] + S.w*ki;
    }
  }
  if (lastlev){
    // ---- fused readout finalize + MLP + log_softmax ----
    __syncthreads();
    if (t < 128){
      float a = L1b[t];
      for (int i = 0; i < 256; i++) a += zr[i]*L1W[i*128 + t];
      h1[t] = fmaxf(a, 0.f);
    }
    __syncthreads();
    if (t < 64){
      float a = L2b[t];
      for (int i = 0; i < 128; i++) a += h1[i]*L2W[i*64 + t];
      h2[t] = fmaxf(a, 0.f);
    }
    __syncthreads();
    if (t == 0){
      float mxv = -INFINITY;
      for (int i = 0; i < 64; i++) mxv = fmaxf(mxv, h2[i]);
      float s = 0.f;
      for (int i = 0; i < 64; i++) s += expf(h2[i] - mxv);
      red[0] = mxv; red[1] = logf(s);
    }
    __syncthreads();
    if (t < 64) out[g*64 + t] = h2[t] - red[0] - red[1];
    return;
  }
  // ---- mapping ----
  if (act) map[t] = -1;
  if (t < k) sb[t] = 0;
  __syncthreads();
  if (t < k) map[si[t]] = t;
  __syncthreads();
  // ---- relabel (register-buffered) + next degree count ----
  int2 ebuf[EIT];
  #pragma unroll
  for (int it = 0; it < EIT; it++){
    int i = ebase + it*512 + t;
    int2 e = edges[i];
    int2 ne = make_int2(-1, 0);
    if (e.x >= 0){
      int ns = map[e.x - gbase], nd = map[e.y - gbase];
      if (ns >= 0 && nd >= 0){
        ne = make_int2(gb2 + ns, gb2 + nd);
        atomicAdd(&sb[nd], 1);
      }
    }
    ebuf[it] = ne;
    edges[i] = ne;
  }
  __syncthreads();
  // ---- scan new degrees -> rowptr/cnt/dinv/cursor ----
  int vdeg = (t < k) ? sb[t] : 0;
  for (int off = 1; off < k; off <<= 1){
    int add = (t >= off && t < k) ? sb[t-off] : 0;
    __syncthreads();
    if (t < k) sb[t] += add;
    __syncthreads();
  }
  if (t < k){
    int excl = sb[t] - vdeg;
    rowptr[gb2 + t] = ebase + excl;
    cnt[gb2 + t] = vdeg;
    cur[t] = excl;
    float dv = rsqrtf((float)vdeg + 1.f);
    dl[t] = dv;
    dinv[gb2 + t] = dv;
  }
  __syncthreads();
  // ---- next-level CSR fill ----
  #pragma unroll
  for (int it = 0; it < EIT; it++){
    int2 e = ebuf[it];
    if (e.x >= 0){
      int sl = e.x - gb2, dc = e.y - gb2;
      int pos = atomicAdd(&cur[dc], 1);
      csr[ebase + pos] = make_int2(e.x, __float_as_int(dl[sl]*dl[dc]));
    }
  }
}

extern "C" void kernel_launch(void* const* d_in, const int* in_sizes, int n_in,
                              void* d_out, int out_size, void* d_ws, size_t ws_size,
                              hipStream_t stream){
  (void)in_sizes; (void)n_in; (void)out_size; (void)ws_size;
  const float* x0  = (const float*)d_in[0];
  const int*   s0  = (const int*)  d_in[1];
  const int*   d0  = (const int*)  d_in[2];
  const float* W1  = (const float*)d_in[3];  const float* b1 = (const float*)d_in[4];
  const float* W2  = (const float*)d_in[5];  const float* b2 = (const float*)d_in[6];
  const float* W3  = (const float*)d_in[7];  const float* b3 = (const float*)d_in[8];
  const float* Wp  = (const float*)d_in[9];  const float* bp = (const float*)d_in[10];
  const float* L1W = (const float*)d_in[11]; const float* L1b = (const float*)d_in[12];
  const float* L2W = (const float*)d_in[13]; const float* L2b = (const float*)d_in[14];
  float* out = (float*)d_out;

  // workspace layout (elements). xp buffers overlay dead tails of h/gout.
  float* w = (float*)d_ws;
  float* h     = w; w += 32768*HID;          // L2/L3 XW scratch
  float* gout  = w; w += 32768*HID;
  float* xpA   = h    + 16384*HID;           // level-1 pool out — h tail
  float* xpB   = gout + 16384*HID;           // level-2 pool out — gout tail
  float* xpC   = xpA;                        // level-3 pool out — xpA dead by then
  float* dinvv = w; w += 32768;
  float* hp    = w; w += 32768;
  float* hppt  = w; w += 4*32768;            // L1 hp quarter-partials
  float* z     = w; w += BGR*256;
  int* cnt     = (int*)w; w += 32768;
  int* rowptr  = (int*)w; w += 32768;
  int2* edges  = (int2*)w; w += E_TOT*2;
  int2* csr    = (int2*)w; w += E_TOT*2;

  k_topo0<<<BGR, 512, 0, stream>>>(s0, d0, edges, cnt, rowptr, dinvv, csr, z);

  // level 1: 512 -> 256 (fused gemm+gather, f-quarter blocks)
  k_l1_fused<<<256, 512, 65536, stream>>>(x0, W1, csr, rowptr, cnt, dinvv,
                                          b1, Wp, (float4*)gout, hppt);
  k_mega<<<BGR, 512, 0, stream>>>((const float4*)gout, hp, hppt, 1, csr, rowptr,
                                  cnt, dinvv, bp, edges, (float4*)xpA, z, 512, 0,
                                  L1W, L1b, L2W, L2b, out);
  // level 2: 256 -> 128
  k_gemm8<<<16384/8, HID, 0, stream>>>(xpA, W2, h, HID, 256);
  k_gcn_gather<<<16384/8, 256, 0, stream>>>((const float4*)h, csr, rowptr, cnt, dinvv,
                                            (const float4*)b2, (const float4*)Wp,
                                            (float4*)gout, hp, 256);
  k_mega<<<BGR, 512, 0, stream>>>((const float4*)gout, hp, hppt, 0, csr, rowptr,
                                  cnt, dinvv, bp, edges, (float4*)xpB, z, 256, 0,
                                  L1W, L1b, L2W, L2b, out);
  // level 3: 128 -> 64 (+ fused readout/MLP/log_softmax)
  k_gemm8<<<8192/8, HID, 0, stream>>>(xpB, W3, h, HID, 128);
  k_gcn_gather<<<8192/8, 256, 0, stream>>>((const float4*)h, csr, rowptr, cnt, dinvv,
                                           (const float4*)b3, (const float4*)Wp,
                                           (float4*)gout, hp, 128);
  k_mega<<<BGR, 512, 0, stream>>>((const float4*)gout, hp, hppt, 0, csr, rowptr,
                                  cnt, dinvv, bp, edges, (float4*)xpC, z, 128, 1,
                                  L1W, L1b, L2W, L2b, out);
}